// Round 5
// baseline (3021.638 us; speedup 1.0000x reference)
//
#include <hip/hip_runtime.h>
#include <math.h>

// CTRNN + adaptive DOPRI5 (B=2048, N=1024). Round 5: persistent kernel,
// 256 blocks x 1024 threads (1 block/CU). Batch-sliced pairwise act
// exchange (validated round 4). Fixes vs round 4:
//  - controller: atomicAdd(double) per block + single broadcast read
//    (was: 256 rolled cross-XCD loads per block per step)
//  - spills: 8 elems/thread, k2..k4 in LDS, incremental error accum
//    (k6/k7 storage eliminated) -> ~110 VGPR, no scratch
//  - split pair handshake: release before own-half GEMM, acquire after

typedef float f4 __attribute__((ext_vector_type(4)));
typedef float f32x4 __attribute__((ext_vector_type(4)));
typedef _Float16 half8v __attribute__((ext_vector_type(8)));
typedef _Float16 half4v __attribute__((ext_vector_type(4)));
typedef _Float16 half2v __attribute__((ext_vector_type(2)));

#define NBLK 256
#define NTHR 1024

#define E1c (71.0f / 57600.0f)
#define E3c (-71.0f / 16695.0f)
#define E4c (71.0f / 1920.0f)
#define E5c (-17253.0f / 339200.0f)
#define E6c (22.0f / 525.0f)
#define E7c (-1.0f / 40.0f)

__global__ void k_zero(int* bar, double* gsum) {
  int i = (int)threadIdx.x;
  if (i == 0) { bar[0] = 0; bar[16] = 0; }
  bar[32 + i] = 0;              // pair flags[256]
  if (i < 64) gsum[i] = 0.0;    // per-step error sums
}

__device__ __forceinline__ void gsync(int* arrive, int* release, int epoch) {
  __syncthreads();
  if (threadIdx.x == 0) {
    __threadfence();
    int prev = __hip_atomic_fetch_add(arrive, 1, __ATOMIC_ACQ_REL, __HIP_MEMORY_SCOPE_AGENT);
    if (prev == epoch * NBLK - 1) {
      __hip_atomic_store(release, epoch, __ATOMIC_RELEASE, __HIP_MEMORY_SCOPE_AGENT);
    } else {
      while (__hip_atomic_load(release, __ATOMIC_ACQUIRE, __HIP_MEMORY_SCOPE_AGENT) < epoch)
        __builtin_amdgcn_s_sleep(2);
    }
    __threadfence();
  }
  __syncthreads();
}

__device__ __forceinline__ void prelease(int* flags, int bid, int cnt) {
  __syncthreads();   // all act writes done
  if (threadIdx.x == 0) {
    __threadfence();
    __hip_atomic_store(&flags[bid], cnt, __ATOMIC_RELEASE, __HIP_MEMORY_SCOPE_AGENT);
  }
}

__device__ __forceinline__ void pacquire(int* flags, int partner, int cnt) {
  if (threadIdx.x == 0) {
    while (__hip_atomic_load(&flags[partner], __ATOMIC_ACQUIRE, __HIP_MEMORY_SCOPE_AGENT) < cnt)
      __builtin_amdgcn_s_sleep(1);
  }
  __syncthreads();
  __threadfence();   // order + L1 invalidate before partner reads
}

__device__ __forceinline__ float ftanh(float x) {
  x = fminf(fmaxf(x, -9.0f), 9.0f);
  float e = __expf(2.0f * x);
  return (e - 1.0f) / (e + 1.0f);
}

__device__ __forceinline__ f32x4 mf(half8v a, half8v b, f32x4 c) {
  return __builtin_amdgcn_mfma_f32_16x16x32_f16(a, b, c, 0, 0, 0);
}

// own-half K: A rows from swizzled LDS, B from L2-resident Wh (2 col streams)
__device__ __forceinline__ void gemm_own(const char* ldsA, int lr, int lk,
                                         const _Float16* __restrict__ w0,
                                         const _Float16* __restrict__ w1,
                                         f32x4 acc[2]) {
  const char* ldsRow = ldsA + lr * 1024;
  const int c7 = lr & 7;
#pragma unroll
  for (int q = 0; q < 4; ++q) { acc[0][q] = 0.0f; acc[1][q] = 0.0f; }
#pragma unroll 4
  for (int kk = 0; kk < 512; kk += 32) {
    half8v a = *(const half8v*)(ldsRow + ((((kk >> 3) + lk) ^ c7) << 4));
    half8v b0 = *(const half8v*)(w0 + kk);
    half8v b1 = *(const half8v*)(w1 + kk);
    acc[0] = mf(a, b0, acc[0]);
    acc[1] = mf(a, b1, acc[1]);
  }
}

// partner-half K: A rows from partner's global act (same-XCD L2)
__device__ __forceinline__ void gemm_part(const _Float16* __restrict__ pA,
                                          const _Float16* __restrict__ w0,
                                          const _Float16* __restrict__ w1,
                                          f32x4 acc[2]) {
#pragma unroll 4
  for (int kk = 0; kk < 512; kk += 32) {
    half8v a = *(const half8v*)(pA + kk);
    half8v b0 = *(const half8v*)(w0 + kk);
    half8v b1 = *(const half8v*)(w1 + kk);
    acc[0] = mf(a, b0, acc[0]);
    acc[1] = mf(a, b1, acc[1]);
  }
}

// Stage-S epilogue. 8 elems/thread: e = tl*4+j; row = lk*4+j (block-local),
// col = colBase + wv*32 + tl*16 + lr. k2..k4 live in LDS (thread-indexed),
// k1,k5 in regs; error accumulated incrementally (k6,k7 never stored).
template <int S>
__device__ __forceinline__ void stage_epi(
    const f32x4 acc[2], float h,
    float* y, float* ys, const half2v* dh, float* k1, float* k5, float* err,
    float* kL2, float* kL3, float* kL4,  // &kL[x][0][tid], stride NTHR per e
    const float* itau2, const float* bias2,
    char* ldsW, _Float16* gW, int lr, int lk, int wv, float* k7r, float* errAcc) {
#pragma unroll
  for (int tl = 0; tl < 2; ++tl) {
#pragma unroll
    for (int j = 0; j < 4; ++j) {
      const int e = tl * 4 + j;
      const int row = lk * 4 + j;
      float yv = y[e];
      float ks;
      if constexpr (S == 1) {
        ks = k1[e];
      } else {
        ks = itau2[tl] * ((float)dh[e >> 1][e & 1] + acc[tl][j] - ys[e]);
      }
      if constexpr (S <= 6) {
        float nys;
        if constexpr (S == 1) {
          err[e] = E1c * ks;
          nys = yv + h * (0.2f * ks);
        } else if constexpr (S == 2) {
          kL2[e * NTHR] = ks;
          nys = yv + h * ((3.0f / 40.0f) * k1[e] + (9.0f / 40.0f) * ks);
        } else if constexpr (S == 3) {
          kL3[e * NTHR] = ks;
          err[e] += E3c * ks;
          nys = yv + h * ((44.0f / 45.0f) * k1[e] + (-56.0f / 15.0f) * kL2[e * NTHR] +
                          (32.0f / 9.0f) * ks);
        } else if constexpr (S == 4) {
          kL4[e * NTHR] = ks;
          err[e] += E4c * ks;
          nys = yv + h * ((19372.0f / 6561.0f) * k1[e] + (-25360.0f / 2187.0f) * kL2[e * NTHR] +
                          (64448.0f / 6561.0f) * kL3[e * NTHR] + (-212.0f / 729.0f) * ks);
        } else if constexpr (S == 5) {
          k5[e] = ks;
          err[e] += E5c * ks;
          nys = yv + h * ((9017.0f / 3168.0f) * k1[e] + (-355.0f / 33.0f) * kL2[e * NTHR] +
                          (46732.0f / 5247.0f) * kL3[e * NTHR] + (49.0f / 176.0f) * kL4[e * NTHR] +
                          (-5103.0f / 18656.0f) * ks);
        } else {  // S == 6 -> y5
          err[e] += E6c * ks;
          nys = yv + h * ((35.0f / 384.0f) * k1[e] + (500.0f / 1113.0f) * kL3[e * NTHR] +
                          (125.0f / 192.0f) * kL4[e * NTHR] + (-2187.0f / 6784.0f) * k5[e] +
                          (11.0f / 84.0f) * ks);
        }
        ys[e] = nys;
        float av = ftanh(nys + bias2[tl]);
        int colLoc = wv * 32 + tl * 16 + lr;
        int sw = (colLoc >> 3) ^ (row & 7);
        *(_Float16*)(ldsW + row * 1024 + sw * 16 + (colLoc & 7) * 2) = (_Float16)av;
        gW[row * 512 + colLoc] = (_Float16)av;
      } else {  // S == 7: k7 + error norm
        k7r[e] = ks;
        float ev = h * (err[e] + E7c * ks);
        float sc = 1e-6f + 1e-3f * fmaxf(fabsf(yv), fabsf(ys[e]));
        float r = ev / sc;
        *errAcc += r * r;
      }
    }
  }
}

__global__ __launch_bounds__(NTHR, 4) void k_ode(
    const float* __restrict__ inp, const float* __restrict__ prev,
    const float* __restrict__ tau, const f4* __restrict__ W4,
    const float* __restrict__ iw, const float* __restrict__ bias,
    float* __restrict__ out, int* __restrict__ bar, double* __restrict__ gsum,
    _Float16* __restrict__ Wh, _Float16* __restrict__ actg) {
  __shared__ _Float16 actL[2][16][512];   // 32 KB
  __shared__ float kL[3][8][NTHR];        // 96 KB: k2,k3,k4
  __shared__ float wsum[16];
  __shared__ double sbcD;

  const int tid = (int)threadIdx.x, bid = (int)blockIdx.x;
  const int lane = tid & 63, wv = tid >> 6;           // 16 waves
  const int lr = lane & 15, lk = lane >> 4;
  const int rowGroup = (bid & 7) | ((bid >> 4) << 3); // 0..127
  const int colHalf = (bid >> 3) & 1;
  const int partner = bid ^ 8;                        // same XCD (bid%8)
  const int rowBase = rowGroup * 16;
  const int colBase = colHalf * 512;
  const int ownK0 = colBase, partK0 = colBase ^ 512;

  int* arrive = bar;
  int* release = bar + 16;
  int* flags = bar + 32;

  // --- W -> fp16 cast (each block casts its 4096-float slice) ---
  {
    half4v* Wh4 = (half4v*)Wh;
    int idx = bid * 1024 + tid;
    f4 w = W4[idx];
    half4v o;
#pragma unroll
    for (int j = 0; j < 4; ++j) o[j] = (_Float16)w[j];
    Wh4[idx] = o;
  }

  // --- pointers ---
  _Float16* gw[2];
  const _Float16* pact[2];
#pragma unroll
  for (int b = 0; b < 2; ++b) {
    gw[b] = actg + ((size_t)(b * 2 + colHalf) * 2048 + rowBase) * 512;
    pact[b] = actg + ((size_t)(b * 2 + (colHalf ^ 1)) * 2048 + rowBase) * 512 +
              lr * 512 + lk * 8;
  }
  const int colT0 = colBase + wv * 32 + lr;
  const _Float16* w0o = Wh + (size_t)colT0 * 1024 + lk * 8 + ownK0;
  const _Float16* w1o = Wh + (size_t)(colT0 + 16) * 1024 + lk * 8 + ownK0;
  const _Float16* w0p = Wh + (size_t)colT0 * 1024 + lk * 8 + partK0;
  const _Float16* w1p = Wh + (size_t)(colT0 + 16) * 1024 + lk * 8 + partK0;
  char* lds0 = (char*)&actL[0][0][0];
  char* lds1 = lds0 + 16384;
  float* kL2 = &kL[0][0][tid];
  float* kL3 = &kL[1][0][tid];
  float* kL4 = &kL[2][0][tid];

  // --- state init + act1 -> buf1 ---
  float y[8], ysr[8], k1r[8], k5r[8], errr[8], k7r[8];
  half2v dh[4];
  float itau2[2], bias2[2];
#pragma unroll
  for (int tl = 0; tl < 2; ++tl) {
    int col = colBase + wv * 32 + tl * 16 + lr;
    itau2[tl] = 1.0f / tau[col];
    bias2[tl] = bias[col];
  }
#pragma unroll
  for (int tl = 0; tl < 2; ++tl) {
#pragma unroll
    for (int j = 0; j < 4; ++j) {
      const int e = tl * 4 + j;
      const int row = lk * 4 + j;
      int colLoc = wv * 32 + tl * 16 + lr;
      int col = colBase + colLoc;
      size_t off = (size_t)(rowBase + row) * 1024 + col;
      float yv = prev[off];
      y[e] = yv;
      ysr[e] = yv;
      dh[e >> 1][e & 1] = (_Float16)(inp[off] * iw[col]);
      float av = ftanh(yv + bias2[tl]);
      int sw = (colLoc >> 3) ^ (row & 7);
      *(_Float16*)(lds1 + row * 1024 + sw * 16 + (colLoc & 7) * 2) = (_Float16)av;
      gw[1][row * 512 + colLoc] = (_Float16)av;
    }
  }

  int ep = 1;
  gsync(arrive, release, ep);   // W cast + act1 visible everywhere

  f32x4 acc[2];
  gemm_own(lds1, lr, lk, w0o, w1o, acc);
  gemm_part(pact[1], w0p, w1p, acc);
#pragma unroll
  for (int tl = 0; tl < 2; ++tl)
#pragma unroll
    for (int j = 0; j < 4; ++j) {
      const int e = tl * 4 + j;
      k1r[e] = itau2[tl] * ((float)dh[e >> 1][e & 1] + acc[tl][j] - y[e]);
    }

  float t = 0.0f, dtv = 0.1f;
  int pcnt = 0;
#pragma unroll 1
  for (int s = 0; s < 40; ++s) {
    if (t >= 1.0f - 1e-7f) break;
    float h = fminf(dtv, 1.0f - t);

    stage_epi<1>(acc, h, y, ysr, dh, k1r, k5r, errr, kL2, kL3, kL4,
                 itau2, bias2, lds0, gw[0], lr, lk, wv, k7r, nullptr);
    prelease(flags, bid, ++pcnt);
    gemm_own(lds0, lr, lk, w0o, w1o, acc);
    pacquire(flags, partner, pcnt);
    gemm_part(pact[0], w0p, w1p, acc);

    stage_epi<2>(acc, h, y, ysr, dh, k1r, k5r, errr, kL2, kL3, kL4,
                 itau2, bias2, lds1, gw[1], lr, lk, wv, k7r, nullptr);
    prelease(flags, bid, ++pcnt);
    gemm_own(lds1, lr, lk, w0o, w1o, acc);
    pacquire(flags, partner, pcnt);
    gemm_part(pact[1], w0p, w1p, acc);

    stage_epi<3>(acc, h, y, ysr, dh, k1r, k5r, errr, kL2, kL3, kL4,
                 itau2, bias2, lds0, gw[0], lr, lk, wv, k7r, nullptr);
    prelease(flags, bid, ++pcnt);
    gemm_own(lds0, lr, lk, w0o, w1o, acc);
    pacquire(flags, partner, pcnt);
    gemm_part(pact[0], w0p, w1p, acc);

    stage_epi<4>(acc, h, y, ysr, dh, k1r, k5r, errr, kL2, kL3, kL4,
                 itau2, bias2, lds1, gw[1], lr, lk, wv, k7r, nullptr);
    prelease(flags, bid, ++pcnt);
    gemm_own(lds1, lr, lk, w0o, w1o, acc);
    pacquire(flags, partner, pcnt);
    gemm_part(pact[1], w0p, w1p, acc);

    stage_epi<5>(acc, h, y, ysr, dh, k1r, k5r, errr, kL2, kL3, kL4,
                 itau2, bias2, lds0, gw[0], lr, lk, wv, k7r, nullptr);
    prelease(flags, bid, ++pcnt);
    gemm_own(lds0, lr, lk, w0o, w1o, acc);
    pacquire(flags, partner, pcnt);
    gemm_part(pact[0], w0p, w1p, acc);

    stage_epi<6>(acc, h, y, ysr, dh, k1r, k5r, errr, kL2, kL3, kL4,
                 itau2, bias2, lds1, gw[1], lr, lk, wv, k7r, nullptr);
    prelease(flags, bid, ++pcnt);
    gemm_own(lds1, lr, lk, w0o, w1o, acc);
    pacquire(flags, partner, pcnt);
    gemm_part(pact[1], w0p, w1p, acc);

    float errAcc = 0.0f;
    stage_epi<7>(acc, h, y, ysr, dh, k1r, k5r, errr, kL2, kL3, kL4,
                 itau2, bias2, nullptr, nullptr, lr, lk, wv, k7r, &errAcc);
#pragma unroll
    for (int o = 32; o > 0; o >>= 1) errAcc += __shfl_down(errAcc, o, 64);
    if (lane == 0) wsum[wv] = errAcc;
    __syncthreads();
    if (tid == 0) {
      float sblk = 0.0f;
#pragma unroll
      for (int w = 0; w < 16; ++w) sblk += wsum[w];
      atomicAdd(&gsum[s], (double)sblk);
    }
    ++ep;
    gsync(arrive, release, ep);

    if (tid == 0)
      sbcD = __hip_atomic_load(&gsum[s], __ATOMIC_ACQUIRE, __HIP_MEMORY_SCOPE_AGENT);
    __syncthreads();
    double sd = sbcD;
    float enorm = fmaxf(sqrtf((float)(sd / (2048.0 * 1024.0))), 1e-10f);
    if (enorm <= 1.0f) {
      t = t + h;
#pragma unroll
      for (int e = 0; e < 8; ++e) { y[e] = ysr[e]; k1r[e] = k7r[e]; }
    }
    float factor = fminf(fmaxf(0.9f * powf(enorm, -0.2f), 0.2f), 5.0f);
    dtv = dtv * factor;
  }

  // --- final output ---
#pragma unroll
  for (int tl = 0; tl < 2; ++tl)
#pragma unroll
    for (int j = 0; j < 4; ++j) {
      const int e = tl * 4 + j;
      const int row = lk * 4 + j;
      int col = colBase + wv * 32 + tl * 16 + lr;
      out[(size_t)(rowBase + row) * 1024 + col] = y[e];
    }
}

extern "C" void kernel_launch(void* const* d_in, const int* in_sizes, int n_in,
                              void* d_out, int out_size, void* d_ws, size_t ws_size,
                              hipStream_t stream) {
  const float* inp = (const float*)d_in[0];
  const float* prev = (const float*)d_in[1];
  const float* tau = (const float*)d_in[2];
  const f4* W4 = (const f4*)d_in[3];
  const float* iw = (const float*)d_in[4];
  const float* bias = (const float*)d_in[5];
  float* out = (float*)d_out;

  char* ws = (char*)d_ws;
  const size_t MB = 1024 * 1024;
  int* bar = (int*)ws;                           // arrive[0], release[16], flags[32..287]
  double* gsum = (double*)(ws + 2048);           // 40 (cleared 64) doubles
  _Float16* Wh = (_Float16*)(ws + 64 * 1024);    // 2 MB
  _Float16* actg = (_Float16*)(ws + 64 * 1024 + 2 * MB);  // 8 MB (2 buf x 2 half)

  k_zero<<<1, 256, 0, stream>>>(bar, gsum);
  k_ode<<<NBLK, NTHR, 0, stream>>>(inp, prev, tau, W4, iw, bias, out,
                                   bar, gsum, Wh, actg);
}

// Round 6
// 1864.246 us; speedup vs baseline: 1.6208x; 1.6208x over previous
//
#include <hip/hip_runtime.h>
#include <math.h>

// CTRNN + adaptive DOPRI5 (B=2048, N=1024). Round 6: 40 step-kernel
// launches (dead steps return immediately). Per-step kernel: 256 blocks x
// 512 thr, block owns 256 rows x 32 cols; W col-tile (64KB fp16) LDS-resident
// across the step's 6 GEMMs; act exchanged XCD-locally (rowgroup = bid&7)
// with 32-block epoch barriers; 1 grid barrier per step for the error norm.
// ODE state (y ping-pong, k1..k6) in global ws. FSAL: stage 1 has no GEMM.

typedef float f4 __attribute__((ext_vector_type(4)));
typedef float f32x4 __attribute__((ext_vector_type(4)));
typedef _Float16 half8v __attribute__((ext_vector_type(8)));
typedef _Float16 half4v __attribute__((ext_vector_type(4)));

#define AS1 __attribute__((address_space(1)))
#define AS3 __attribute__((address_space(3)))

#define NBLK 256
#define NTHR 512
#define TOT ((size_t)2048 * 1024)

#define E1c (71.0f / 57600.0f)
#define E3c (-71.0f / 16695.0f)
#define E4c (71.0f / 1920.0f)
#define E5c (-17253.0f / 339200.0f)
#define E6c (22.0f / 525.0f)
#define E7c (-1.0f / 40.0f)

struct Ctl { float t, dt; int ysel, alc; };

__global__ void k_zero(int* bar, double* gsum, Ctl* c) {
  int i = (int)threadIdx.x;
  if (i < 128) bar[i] = 0;
  if (i < 64) gsum[i] = 0.0;
  if (i == 0) { c->t = 0.0f; c->dt = 0.1f; c->ysel = 0; c->alc = 0; }
}

__device__ __forceinline__ float ftanh(float x) {
  x = fminf(fmaxf(x, -9.0f), 9.0f);
  float e = __expf(2.0f * x);
  return (e - 1.0f) / (e + 1.0f);
}

__global__ void k_prep(const f4* __restrict__ W, half4v* __restrict__ Wh) {
  int i = blockIdx.x * blockDim.x + threadIdx.x;
  f4 w = W[i];
  half4v o;
#pragma unroll
  for (int j = 0; j < 4; ++j) o[j] = (_Float16)w[j];
  Wh[i] = o;
}

__global__ void k_init(const f4* __restrict__ prev, const f4* __restrict__ bias,
                       f4* __restrict__ y0, half4v* __restrict__ act1) {
  int i = blockIdx.x * blockDim.x + threadIdx.x;
  f4 v = prev[i];
  y0[i] = v;
  f4 b = bias[i & 255];
  half4v a;
#pragma unroll
  for (int j = 0; j < 4; ++j) a[j] = (_Float16)ftanh(v[j] + b[j]);
  act1[i] = a;
}

__global__ void k_final(const Ctl* __restrict__ c, f4* __restrict__ yA,
                        const f4* __restrict__ yB) {
  if (!(c->ysel & 1)) return;
  int i = blockIdx.x * blockDim.x + threadIdx.x;
  yA[i] = yB[i];
}

// 32-block rowgroup barrier (epoch-based, counters never reset)
__device__ __forceinline__ void rowbar(int* bar, int rg, int e) {
  __syncthreads();
  if (threadIdx.x == 0) {
    __threadfence();
    int prev = __hip_atomic_fetch_add(&bar[32 + rg], 1, __ATOMIC_ACQ_REL, __HIP_MEMORY_SCOPE_AGENT);
    if (prev == e * 32 - 1) {
      __hip_atomic_store(&bar[64 + rg], e, __ATOMIC_RELEASE, __HIP_MEMORY_SCOPE_AGENT);
    } else {
      while (__hip_atomic_load(&bar[64 + rg], __ATOMIC_ACQUIRE, __HIP_MEMORY_SCOPE_AGENT) < e)
        __builtin_amdgcn_s_sleep(1);
    }
    __threadfence();
  }
  __syncthreads();
}

__device__ __forceinline__ void gsync(int* bar, int e) {
  __syncthreads();
  if (threadIdx.x == 0) {
    __threadfence();
    int prev = __hip_atomic_fetch_add(&bar[0], 1, __ATOMIC_ACQ_REL, __HIP_MEMORY_SCOPE_AGENT);
    if (prev == e * NBLK - 1) {
      __hip_atomic_store(&bar[16], e, __ATOMIC_RELEASE, __HIP_MEMORY_SCOPE_AGENT);
    } else {
      while (__hip_atomic_load(&bar[16], __ATOMIC_ACQUIRE, __HIP_MEMORY_SCOPE_AGENT) < e)
        __builtin_amdgcn_s_sleep(2);
    }
    __threadfence();
  }
  __syncthreads();
}

// rec tile [256 x 32] = act[256 rows,1024] @ W_tile[32 cols,1024]^T.
// A double-buffered through LDS (global_load_lds, pre-swizzled source);
// B from LDS-resident swizzled W tile.
__device__ __forceinline__ void gemm(const _Float16* __restrict__ act,
                                     _Float16* As, const _Float16* Ws,
                                     int rowBase, int tid, int wv, int lr, int lk,
                                     f32x4 acc[2][2]) {
#pragma unroll
  for (int m = 0; m < 2; ++m)
#pragma unroll
    for (int n = 0; n < 2; ++n)
#pragma unroll
      for (int q = 0; q < 4; ++q) acc[m][n][q] = 0.0f;
#pragma unroll
  for (int u = 0; u < 4; ++u) {
    int slot = u * NTHR + tid;
    int row = slot >> 3, ch = slot & 7;
    __builtin_amdgcn_global_load_lds(
        (const AS1 void*)(act + (size_t)(rowBase + row) * 1024 + ((ch ^ (row & 7)) << 3)),
        (AS3 void*)(As + slot * 8), 16, 0, 0);
  }
  __syncthreads();
#pragma unroll 2
  for (int it = 0; it < 16; ++it) {
    const _Float16* Ac = As + (it & 1) * 16384;
    if (it < 15) {
      int k0n = (it + 1) << 6;
      _Float16* An = As + ((it + 1) & 1) * 16384;
#pragma unroll
      for (int u = 0; u < 4; ++u) {
        int slot = u * NTHR + tid;
        int row = slot >> 3, ch = slot & 7;
        __builtin_amdgcn_global_load_lds(
            (const AS1 void*)(act + (size_t)(rowBase + row) * 1024 + k0n + ((ch ^ (row & 7)) << 3)),
            (AS3 void*)(An + slot * 8), 16, 0, 0);
      }
    }
    half8v af[2][2], bf[2][2];
#pragma unroll
    for (int m = 0; m < 2; ++m) {
      int row = wv * 32 + m * 16 + lr;
#pragma unroll
      for (int ks = 0; ks < 2; ++ks)
        af[m][ks] = *(const half8v*)(Ac + row * 64 + (((ks * 4 + lk) ^ (row & 7)) << 3));
    }
#pragma unroll
    for (int n = 0; n < 2; ++n) {
      int lc = n * 16 + lr;
#pragma unroll
      for (int ks = 0; ks < 2; ++ks) {
        int chunk = (it << 3) + ks * 4 + lk;
        bf[n][ks] = *(const half8v*)(Ws + lc * 1024 + ((chunk ^ (lc & 7)) << 3));
      }
    }
#pragma unroll
    for (int ks = 0; ks < 2; ++ks)
#pragma unroll
      for (int m = 0; m < 2; ++m)
#pragma unroll
        for (int n = 0; n < 2; ++n)
          acc[m][n] = __builtin_amdgcn_mfma_f32_16x16x32_f16(af[m][ks], bf[n][ks], acc[m][n], 0, 0, 0);
    __syncthreads();
  }
}

template <int S>
__device__ __forceinline__ void ep_stage(
    const f32x4 acc[2][2], float h, int li,
    const float* __restrict__ y, float* __restrict__ ys,
    float* __restrict__ kb, const float* __restrict__ inp,
    const float* itau2, const float* iw2, const float* bias2,
    _Float16* __restrict__ actOut,
    int rowBase, int colBase, int wv, int lr, int lk,
    float* k7r, float* errAcc) {
  float* kb0 = kb;
  float* kb1 = kb + TOT;
  float* kb2 = kb + 2 * TOT;
  float* kb3 = kb + 3 * TOT;
  float* kb4 = kb + 4 * TOT;
  float* kb5 = kb + 5 * TOT;
#pragma unroll
  for (int m = 0; m < 2; ++m) {
#pragma unroll
    for (int j = 0; j < 4; ++j) {
      size_t rowo = (size_t)(rowBase + wv * 32 + m * 16 + lk * 4 + j) * 1024;
#pragma unroll
      for (int n = 0; n < 2; ++n) {
        size_t off = rowo + colBase + n * 16 + lr;
        float yv = y[off];
        float drive = inp[off] * iw2[n];
        float nys;
        if constexpr (S == 1) {
          float k1;
          if (li == 0) {
            k1 = itau2[n] * (drive + acc[m][n][j] - yv);
            kb0[off] = k1;
          } else {
            k1 = kb0[off];
          }
          nys = yv + h * (0.2f * k1);
        } else {
          float ysv = ys[off];
          float ks = itau2[n] * (drive + acc[m][n][j] - ysv);
          if constexpr (S == 2) {
            kb1[off] = ks;
            nys = yv + h * ((3.0f / 40.0f) * kb0[off] + (9.0f / 40.0f) * ks);
          } else if constexpr (S == 3) {
            kb2[off] = ks;
            nys = yv + h * ((44.0f / 45.0f) * kb0[off] + (-56.0f / 15.0f) * kb1[off] +
                            (32.0f / 9.0f) * ks);
          } else if constexpr (S == 4) {
            kb3[off] = ks;
            nys = yv + h * ((19372.0f / 6561.0f) * kb0[off] + (-25360.0f / 2187.0f) * kb1[off] +
                            (64448.0f / 6561.0f) * kb2[off] + (-212.0f / 729.0f) * ks);
          } else if constexpr (S == 5) {
            kb4[off] = ks;
            nys = yv + h * ((9017.0f / 3168.0f) * kb0[off] + (-355.0f / 33.0f) * kb1[off] +
                            (46732.0f / 5247.0f) * kb2[off] + (49.0f / 176.0f) * kb3[off] +
                            (-5103.0f / 18656.0f) * ks);
          } else if constexpr (S == 6) {
            kb5[off] = ks;
            nys = yv + h * ((35.0f / 384.0f) * kb0[off] + (500.0f / 1113.0f) * kb2[off] +
                            (125.0f / 192.0f) * kb3[off] + (-2187.0f / 6784.0f) * kb4[off] +
                            (11.0f / 84.0f) * ks);
          } else {  // S == 7
            k7r[m * 8 + j * 2 + n] = ks;
            float ev = h * (E1c * kb0[off] + E3c * kb2[off] + E4c * kb3[off] +
                            E5c * kb4[off] + E6c * kb5[off] + E7c * ks);
            float sc = 1e-6f + 1e-3f * fmaxf(fabsf(yv), fabsf(ysv));
            float r = ev / sc;
            *errAcc += r * r;
            nys = 0.0f;  // unused
          }
        }
        if constexpr (S <= 6) {
          ys[off] = nys;
          actOut[off] = (_Float16)ftanh(nys + bias2[n]);
        }
      }
    }
  }
}

__global__ __launch_bounds__(NTHR, 2) void k_step(
    int li, Ctl* __restrict__ c, int* __restrict__ bar, double* __restrict__ gsum,
    const _Float16* __restrict__ Wh, _Float16* __restrict__ ab0,
    _Float16* __restrict__ ab1, float* __restrict__ yA, float* __restrict__ yB,
    float* __restrict__ kb, const float* __restrict__ inp,
    const float* __restrict__ iw, const float* __restrict__ tau,
    const float* __restrict__ bias) {
  float t = c->t;
  if (t >= 1.0f - 1e-7f) return;

  __shared__ _Float16 Ws[32 * 1024];      // 64 KB W col-tile (swizzled)
  __shared__ _Float16 As[2 * 2048 * 8];   // 64 KB A double-buffer
  __shared__ float wsum[8];

  const int tid = (int)threadIdx.x, bid = (int)blockIdx.x;
  const int lane = tid & 63, wv = tid >> 6;
  const int lr = lane & 15, lk = lane >> 4;
  const int rg = bid & 7, cg = bid >> 3;        // rowgroup = XCD-local
  const int rowBase = rg * 256, colBase = cg * 32;
  const float dtv = c->dt;
  const float h = fminf(dtv, 1.0f - t);
  const int sel = c->ysel, alc = c->alc;
  float* y = sel ? yB : yA;
  float* ys = sel ? yA : yB;

  // --- W col-tile -> LDS (pre-swizzled source, linear dest) ---
#pragma unroll
  for (int u = 0; u < 8; ++u) {
    int slot = u * NTHR + tid;                  // 0..4095
    int lc = slot >> 7, phys = slot & 127;
    __builtin_amdgcn_global_load_lds(
        (const AS1 void*)(Wh + (size_t)(colBase + lc) * 1024 + ((phys ^ (lc & 7)) << 3)),
        (AS3 void*)(Ws + slot * 8), 16, 0, 0);
  }

  float itau2[2], iw2[2], bias2[2];
#pragma unroll
  for (int n = 0; n < 2; ++n) {
    int col = colBase + n * 16 + lr;
    itau2[n] = 1.0f / tau[col];
    iw2[n] = iw[col];
    bias2[n] = bias[col];
  }

  const int rb = alc * 6;
  f32x4 acc[2][2];

  // stage 1 (FSAL: GEMM only on the very first launch)
  if (li == 0) gemm(ab1, As, Ws, rowBase, tid, wv, lr, lk, acc);
  ep_stage<1>(acc, h, li, y, ys, kb, inp, itau2, iw2, bias2, ab0,
              rowBase, colBase, wv, lr, lk, nullptr, nullptr);
  rowbar(bar, rg, rb + 1);

  gemm(ab0, As, Ws, rowBase, tid, wv, lr, lk, acc);
  ep_stage<2>(acc, h, li, y, ys, kb, inp, itau2, iw2, bias2, ab1,
              rowBase, colBase, wv, lr, lk, nullptr, nullptr);
  rowbar(bar, rg, rb + 2);

  gemm(ab1, As, Ws, rowBase, tid, wv, lr, lk, acc);
  ep_stage<3>(acc, h, li, y, ys, kb, inp, itau2, iw2, bias2, ab0,
              rowBase, colBase, wv, lr, lk, nullptr, nullptr);
  rowbar(bar, rg, rb + 3);

  gemm(ab0, As, Ws, rowBase, tid, wv, lr, lk, acc);
  ep_stage<4>(acc, h, li, y, ys, kb, inp, itau2, iw2, bias2, ab1,
              rowBase, colBase, wv, lr, lk, nullptr, nullptr);
  rowbar(bar, rg, rb + 4);

  gemm(ab1, As, Ws, rowBase, tid, wv, lr, lk, acc);
  ep_stage<5>(acc, h, li, y, ys, kb, inp, itau2, iw2, bias2, ab0,
              rowBase, colBase, wv, lr, lk, nullptr, nullptr);
  rowbar(bar, rg, rb + 5);

  gemm(ab0, As, Ws, rowBase, tid, wv, lr, lk, acc);
  ep_stage<6>(acc, h, li, y, ys, kb, inp, itau2, iw2, bias2, ab1,
              rowBase, colBase, wv, lr, lk, nullptr, nullptr);
  rowbar(bar, rg, rb + 6);

  gemm(ab1, As, Ws, rowBase, tid, wv, lr, lk, acc);
  float k7r[16];
  float errAcc = 0.0f;
  ep_stage<7>(acc, h, li, y, ys, kb, inp, itau2, iw2, bias2, nullptr,
              rowBase, colBase, wv, lr, lk, k7r, &errAcc);

#pragma unroll
  for (int o = 32; o > 0; o >>= 1) errAcc += __shfl_down(errAcc, o, 64);
  if (lane == 0) wsum[wv] = errAcc;
  __syncthreads();
  if (tid == 0) {
    float sblk = 0.0f;
#pragma unroll
    for (int w = 0; w < 8; ++w) sblk += wsum[w];
    atomicAdd(&gsum[li], (double)sblk);
  }
  gsync(bar, alc + 1);

  double sd = __hip_atomic_load(&gsum[li], __ATOMIC_ACQUIRE, __HIP_MEMORY_SCOPE_AGENT);
  float enorm = fmaxf(sqrtf((float)(sd / (double)TOT)), 1e-10f);
  bool acceptS = (enorm <= 1.0f);
  if (acceptS) {
    // FSAL: k7 becomes next step's k1 (own tile only)
#pragma unroll
    for (int m = 0; m < 2; ++m)
#pragma unroll
      for (int j = 0; j < 4; ++j) {
        size_t rowo = (size_t)(rowBase + wv * 32 + m * 16 + lk * 4 + j) * 1024;
#pragma unroll
        for (int n = 0; n < 2; ++n)
          kb[rowo + colBase + n * 16 + lr] = k7r[m * 8 + j * 2 + n];
      }
  }
  if (bid == 0 && tid == 0) {
    float factor = fminf(fmaxf(0.9f * powf(enorm, -0.2f), 0.2f), 5.0f);
    c->dt = dtv * factor;
    if (acceptS) { c->t = t + h; c->ysel = sel ^ 1; }
    c->alc = alc + 1;
  }
}

extern "C" void kernel_launch(void* const* d_in, const int* in_sizes, int n_in,
                              void* d_out, int out_size, void* d_ws, size_t ws_size,
                              hipStream_t stream) {
  const float* inp = (const float*)d_in[0];
  const f4* prev = (const f4*)d_in[1];
  const float* tau = (const float*)d_in[2];
  const f4* W4 = (const f4*)d_in[3];
  const float* iw = (const float*)d_in[4];
  const float* bias = (const float*)d_in[5];
  float* yA = (float*)d_out;

  char* ws = (char*)d_ws;
  const size_t MB = 1024 * 1024;
  Ctl* c = (Ctl*)ws;
  int* bar = (int*)(ws + 256);
  double* gsum = (double*)(ws + 1024);
  _Float16* Wh = (_Float16*)(ws + 64 * 1024);           // 2 MB
  _Float16* ab0 = (_Float16*)(ws + 64 * 1024 + 2 * MB); // 4 MB
  _Float16* ab1 = (_Float16*)(ws + 64 * 1024 + 6 * MB); // 4 MB
  float* yB = (float*)(ws + 64 * 1024 + 10 * MB);       // 8 MB
  float* kb = (float*)(ws + 64 * 1024 + 18 * MB);       // 48 MB (k1..k6)

  k_zero<<<1, 128, 0, stream>>>(bar, gsum, c);
  k_prep<<<1024, 256, 0, stream>>>(W4, (half4v*)Wh);
  k_init<<<2048, 256, 0, stream>>>(prev, (const f4*)bias, (f4*)yA, (half4v*)ab1);
  for (int s = 0; s < 40; ++s) {
    k_step<<<NBLK, NTHR, 0, stream>>>(s, c, bar, gsum, Wh, ab0, ab1, yA, yB, kb,
                                      inp, iw, tau, bias);
  }
  k_final<<<2048, 256, 0, stream>>>(c, (f4*)yA, (const f4*)yB);
}

// Round 7
// 1351.450 us; speedup vs baseline: 2.2358x; 1.3794x over previous
//
#include <hip/hip_runtime.h>
#include <math.h>

// CTRNN + adaptive DOPRI5 (B=2048, N=1024). Round 7: single persistent
// kernel, 256 blocks x 512 thr (1 block/CU, 128KB LDS). Block owns a
// 256-row x 32-col output tile (rowgroup = bid&7 -> XCD-local act reuse).
// Per-stage state: y/ys/k1/err/drive in registers (80 VGPR), k2..k5 as
// fp16 in LDS (64KB), As double-buffer 64KB. W fp16 fragments read
// per-wave from L2 (no W LDS). FSAL: k1=k7 on accept -> stage 1 has no
// GEMM; 6 GEMMs per step. Controller: 1 atomicAdd(double)/block +
// broadcast read after the step's single grid sync. Dead steps: break.

typedef float f4 __attribute__((ext_vector_type(4)));
typedef float f32x4 __attribute__((ext_vector_type(4)));
typedef _Float16 half8v __attribute__((ext_vector_type(8)));
typedef _Float16 half4v __attribute__((ext_vector_type(4)));

#define AS1 __attribute__((address_space(1)))
#define AS3 __attribute__((address_space(3)))

#define NBLK 256
#define NTHR 512
#define TOTD (2048.0 * 1024.0)

#define E1c (71.0f / 57600.0f)
#define E3c (-71.0f / 16695.0f)
#define E4c (71.0f / 1920.0f)
#define E5c (-17253.0f / 339200.0f)
#define E6c (22.0f / 525.0f)
#define E7c (-1.0f / 40.0f)

__global__ void k_zero(int* bar, double* gsum) {
  int i = (int)threadIdx.x;
  bar[i] = 0;                    // [0]=g-arrive, [16]=g-release, [32+rg], [64+rg]
  if (i < 64) gsum[i] = 0.0;
}

__device__ __forceinline__ float ftanh(float x) {
  x = fminf(fmaxf(x, -9.0f), 9.0f);
  float e = __expf(2.0f * x);
  return (e - 1.0f) / (e + 1.0f);
}

__device__ __forceinline__ void rowbar(int* bar, int rg, int e) {
  __syncthreads();
  if (threadIdx.x == 0) {
    __threadfence();
    int prev = __hip_atomic_fetch_add(&bar[32 + rg], 1, __ATOMIC_ACQ_REL, __HIP_MEMORY_SCOPE_AGENT);
    if (prev == e * 32 - 1) {
      __hip_atomic_store(&bar[64 + rg], e, __ATOMIC_RELEASE, __HIP_MEMORY_SCOPE_AGENT);
    } else {
      while (__hip_atomic_load(&bar[64 + rg], __ATOMIC_ACQUIRE, __HIP_MEMORY_SCOPE_AGENT) < e)
        __builtin_amdgcn_s_sleep(1);
    }
    __threadfence();
  }
  __syncthreads();
}

__device__ __forceinline__ void gsync(int* bar, int e) {
  __syncthreads();
  if (threadIdx.x == 0) {
    __threadfence();
    int prev = __hip_atomic_fetch_add(&bar[0], 1, __ATOMIC_ACQ_REL, __HIP_MEMORY_SCOPE_AGENT);
    if (prev == e * NBLK - 1) {
      __hip_atomic_store(&bar[16], e, __ATOMIC_RELEASE, __HIP_MEMORY_SCOPE_AGENT);
    } else {
      while (__hip_atomic_load(&bar[16], __ATOMIC_ACQUIRE, __HIP_MEMORY_SCOPE_AGENT) < e)
        __builtin_amdgcn_s_sleep(2);
    }
    __threadfence();
  }
  __syncthreads();
}

// rec tile [256x32] = act[256,1024] @ W[32,1024]^T. A through LDS
// (global_load_lds, pre-swizzled source, double-buffered BK=64); W 16B
// fragments per-wave from global (L2-resident Wh).
__device__ __forceinline__ void gemm(const _Float16* __restrict__ act,
                                     const _Float16* __restrict__ wp0,
                                     const _Float16* __restrict__ wp1,
                                     _Float16* As, int rowBase, int tid,
                                     int wv, int lr, int lk, f32x4 acc[2][2]) {
#pragma unroll
  for (int m = 0; m < 2; ++m)
#pragma unroll
    for (int n = 0; n < 2; ++n)
#pragma unroll
      for (int q = 0; q < 4; ++q) acc[m][n][q] = 0.0f;
#pragma unroll
  for (int u = 0; u < 4; ++u) {
    int slot = u * NTHR + tid;
    int row = slot >> 3, ch = slot & 7;
    __builtin_amdgcn_global_load_lds(
        (const AS1 void*)(act + (size_t)(rowBase + row) * 1024 + ((ch ^ (row & 7)) << 3)),
        (AS3 void*)(As + slot * 8), 16, 0, 0);
  }
#pragma unroll 1
  for (int it = 0; it < 16; ++it) {
    __syncthreads();   // chunk `it` ready (drains vmcnt); prev reads done
    const _Float16* Ac = As + (it & 1) * 16384;
    if (it < 15) {
      _Float16* An = As + ((it + 1) & 1) * 16384;
      int k0n = (it + 1) << 6;
#pragma unroll
      for (int u = 0; u < 4; ++u) {
        int slot = u * NTHR + tid;
        int row = slot >> 3, ch = slot & 7;
        __builtin_amdgcn_global_load_lds(
            (const AS1 void*)(act + (size_t)(rowBase + row) * 1024 + k0n + ((ch ^ (row & 7)) << 3)),
            (AS3 void*)(An + slot * 8), 16, 0, 0);
      }
    }
    half8v bf[2][2];
#pragma unroll
    for (int ks = 0; ks < 2; ++ks) {
      bf[0][ks] = *(const half8v*)(wp0 + (it << 6) + ks * 32);
      bf[1][ks] = *(const half8v*)(wp1 + (it << 6) + ks * 32);
    }
    half8v af[2][2];
#pragma unroll
    for (int m = 0; m < 2; ++m) {
      int row = wv * 32 + m * 16 + lr;
#pragma unroll
      for (int ks = 0; ks < 2; ++ks)
        af[m][ks] = *(const half8v*)(Ac + row * 64 + (((ks * 4 + lk) ^ (row & 7)) << 3));
    }
#pragma unroll
    for (int ks = 0; ks < 2; ++ks)
#pragma unroll
      for (int m = 0; m < 2; ++m)
#pragma unroll
        for (int n = 0; n < 2; ++n)
          acc[m][n] = __builtin_amdgcn_mfma_f32_16x16x32_f16(af[m][ks], bf[n][ks], acc[m][n], 0, 0, 0);
  }
}

// e = m*8 + j*2 + n. kLs: fp16 [4][16][512] thread-indexed.
template <int S>
__device__ __forceinline__ void stage_epi(
    const f32x4 acc[2][2], float h,
    const float* y, float* ys, const float* drive, float* k1, float* err,
    _Float16* kLs, int tid,
    const float* itau2, const float* bias2,
    _Float16* __restrict__ actOut, int rowBase, int colBase,
    int wv, int lr, int lk, float* k7r, float* errAcc) {
#pragma unroll
  for (int m = 0; m < 2; ++m) {
#pragma unroll
    for (int j = 0; j < 4; ++j) {
#pragma unroll
      for (int n = 0; n < 2; ++n) {
        const int e = m * 8 + j * 2 + n;
        float yv = y[e];
        float ks;
        if constexpr (S == 1) {
          ks = k1[e];
        } else {
          ks = itau2[n] * (drive[e] + acc[m][n][j] - ys[e]);
        }
        float nys;
        if constexpr (S == 1) {
          err[e] = E1c * ks;
          nys = yv + h * (0.2f * ks);
        } else if constexpr (S == 2) {
          kLs[(0 * 16 + e) * NTHR + tid] = (_Float16)ks;
          nys = yv + h * ((3.0f / 40.0f) * k1[e] + (9.0f / 40.0f) * ks);
        } else if constexpr (S == 3) {
          kLs[(1 * 16 + e) * NTHR + tid] = (_Float16)ks;
          err[e] += E3c * ks;
          float k2 = (float)kLs[(0 * 16 + e) * NTHR + tid];
          nys = yv + h * ((44.0f / 45.0f) * k1[e] + (-56.0f / 15.0f) * k2 +
                          (32.0f / 9.0f) * ks);
        } else if constexpr (S == 4) {
          kLs[(2 * 16 + e) * NTHR + tid] = (_Float16)ks;
          err[e] += E4c * ks;
          float k2 = (float)kLs[(0 * 16 + e) * NTHR + tid];
          float k3 = (float)kLs[(1 * 16 + e) * NTHR + tid];
          nys = yv + h * ((19372.0f / 6561.0f) * k1[e] + (-25360.0f / 2187.0f) * k2 +
                          (64448.0f / 6561.0f) * k3 + (-212.0f / 729.0f) * ks);
        } else if constexpr (S == 5) {
          kLs[(3 * 16 + e) * NTHR + tid] = (_Float16)ks;
          err[e] += E5c * ks;
          float k2 = (float)kLs[(0 * 16 + e) * NTHR + tid];
          float k3 = (float)kLs[(1 * 16 + e) * NTHR + tid];
          float k4 = (float)kLs[(2 * 16 + e) * NTHR + tid];
          nys = yv + h * ((9017.0f / 3168.0f) * k1[e] + (-355.0f / 33.0f) * k2 +
                          (46732.0f / 5247.0f) * k3 + (49.0f / 176.0f) * k4 +
                          (-5103.0f / 18656.0f) * ks);
        } else if constexpr (S == 6) {
          err[e] += E6c * ks;
          float k3 = (float)kLs[(1 * 16 + e) * NTHR + tid];
          float k4 = (float)kLs[(2 * 16 + e) * NTHR + tid];
          float k5 = (float)kLs[(3 * 16 + e) * NTHR + tid];
          nys = yv + h * ((35.0f / 384.0f) * k1[e] + (500.0f / 1113.0f) * k3 +
                          (125.0f / 192.0f) * k4 + (-2187.0f / 6784.0f) * k5 +
                          (11.0f / 84.0f) * ks);
        } else {  // S == 7
          k7r[e] = ks;
          float ev = h * (err[e] + E7c * ks);
          float sc = 1e-6f + 1e-3f * fmaxf(fabsf(yv), fabsf(ys[e]));
          float r = ev / sc;
          *errAcc += r * r;
          nys = 0.0f;
        }
        if constexpr (S <= 6) {
          ys[e] = nys;
          int row = rowBase + wv * 32 + m * 16 + lk * 4 + j;
          int col = colBase + n * 16 + lr;
          actOut[(size_t)row * 1024 + col] = (_Float16)ftanh(nys + bias2[n]);
        }
      }
    }
  }
}

__global__ __launch_bounds__(NTHR, 2) void k_ode(
    const float* __restrict__ inp, const float* __restrict__ prev,
    const float* __restrict__ tau, const f4* __restrict__ W4,
    const float* __restrict__ iw, const float* __restrict__ bias,
    float* __restrict__ out, int* __restrict__ bar, double* __restrict__ gsum,
    _Float16* __restrict__ Wh, _Float16* __restrict__ ab0,
    _Float16* __restrict__ ab1) {
  __shared__ _Float16 As[2 * 2048 * 8];      // 64 KB A double-buffer
  __shared__ _Float16 kLs[4 * 16 * NTHR];    // 64 KB: k2..k5 fp16
  __shared__ float wsum[8];

  const int tid = (int)threadIdx.x, bid = (int)blockIdx.x;
  const int lane = tid & 63, wv = tid >> 6;
  const int lr = lane & 15, lk = lane >> 4;
  const int rg = bid & 7, cg = bid >> 3;     // 8 rowgroups (XCD-local) x 32 colgroups
  const int rowBase = rg * 256, colBase = cg * 32;

  // --- W -> fp16 (each block its 4096-float slice) ---
  {
    half4v* Wh4 = (half4v*)Wh;
#pragma unroll
    for (int u = 0; u < 2; ++u) {
      int idx = bid * 1024 + u * NTHR + tid;
      f4 w = W4[idx];
      half4v o;
#pragma unroll
      for (int j = 0; j < 4; ++j) o[j] = (_Float16)w[j];
      Wh4[idx] = o;
    }
  }

  // per-wave W fragment base pointers (cols colBase + n*16 + lr)
  const _Float16* wp0 = Wh + (size_t)(colBase + 0 * 16 + lr) * 1024 + lk * 8;
  const _Float16* wp1 = Wh + (size_t)(colBase + 1 * 16 + lr) * 1024 + lk * 8;

  // --- state init + act1 -> ab1 ---
  float y[16], ysr[16], drive[16], k1r[16], errr[16], k7r[16];
  float itau2[2], bias2[2];
#pragma unroll
  for (int n = 0; n < 2; ++n) {
    int col = colBase + n * 16 + lr;
    itau2[n] = 1.0f / tau[col];
    bias2[n] = bias[col];
  }
#pragma unroll
  for (int m = 0; m < 2; ++m)
#pragma unroll
    for (int j = 0; j < 4; ++j)
#pragma unroll
      for (int n = 0; n < 2; ++n) {
        const int e = m * 8 + j * 2 + n;
        int row = rowBase + wv * 32 + m * 16 + lk * 4 + j;
        int col = colBase + n * 16 + lr;
        size_t off = (size_t)row * 1024 + col;
        float yv = prev[off];
        y[e] = yv;
        ysr[e] = yv;
        drive[e] = inp[off] * iw[col];
        ab1[off] = (_Float16)ftanh(yv + bias2[n]);
      }

  int ep = 1;
  gsync(bar, ep);   // W cast + act1 visible

  f32x4 acc[2][2];
  gemm(ab1, wp0, wp1, As, rowBase, tid, wv, lr, lk, acc);   // initial k1
#pragma unroll
  for (int m = 0; m < 2; ++m)
#pragma unroll
    for (int j = 0; j < 4; ++j)
#pragma unroll
      for (int n = 0; n < 2; ++n) {
        const int e = m * 8 + j * 2 + n;
        k1r[e] = itau2[n] * (drive[e] + acc[m][n][j] - y[e]);
      }

  float t = 0.0f, dtv = 0.1f;
#pragma unroll 1
  for (int s = 0; s < 40; ++s) {
    if (t >= 1.0f - 1e-7f) break;
    const float h = fminf(dtv, 1.0f - t);
    const int rb = s * 6;

    stage_epi<1>(acc, h, y, ysr, drive, k1r, errr, kLs, tid, itau2, bias2,
                 ab0, rowBase, colBase, wv, lr, lk, k7r, nullptr);
    rowbar(bar, rg, rb + 1);
    gemm(ab0, wp0, wp1, As, rowBase, tid, wv, lr, lk, acc);

    stage_epi<2>(acc, h, y, ysr, drive, k1r, errr, kLs, tid, itau2, bias2,
                 ab1, rowBase, colBase, wv, lr, lk, k7r, nullptr);
    rowbar(bar, rg, rb + 2);
    gemm(ab1, wp0, wp1, As, rowBase, tid, wv, lr, lk, acc);

    stage_epi<3>(acc, h, y, ysr, drive, k1r, errr, kLs, tid, itau2, bias2,
                 ab0, rowBase, colBase, wv, lr, lk, k7r, nullptr);
    rowbar(bar, rg, rb + 3);
    gemm(ab0, wp0, wp1, As, rowBase, tid, wv, lr, lk, acc);

    stage_epi<4>(acc, h, y, ysr, drive, k1r, errr, kLs, tid, itau2, bias2,
                 ab1, rowBase, colBase, wv, lr, lk, k7r, nullptr);
    rowbar(bar, rg, rb + 4);
    gemm(ab1, wp0, wp1, As, rowBase, tid, wv, lr, lk, acc);

    stage_epi<5>(acc, h, y, ysr, drive, k1r, errr, kLs, tid, itau2, bias2,
                 ab0, rowBase, colBase, wv, lr, lk, k7r, nullptr);
    rowbar(bar, rg, rb + 5);
    gemm(ab0, wp0, wp1, As, rowBase, tid, wv, lr, lk, acc);

    stage_epi<6>(acc, h, y, ysr, drive, k1r, errr, kLs, tid, itau2, bias2,
                 ab1, rowBase, colBase, wv, lr, lk, k7r, nullptr);   // act7 -> ab1
    rowbar(bar, rg, rb + 6);
    gemm(ab1, wp0, wp1, As, rowBase, tid, wv, lr, lk, acc);

    float errAcc = 0.0f;
    stage_epi<7>(acc, h, y, ysr, drive, k1r, errr, kLs, tid, itau2, bias2,
                 nullptr, rowBase, colBase, wv, lr, lk, k7r, &errAcc);
#pragma unroll
    for (int o = 32; o > 0; o >>= 1) errAcc += __shfl_down(errAcc, o, 64);
    if (lane == 0) wsum[wv] = errAcc;
    __syncthreads();
    if (tid == 0) {
      float sblk = 0.0f;
#pragma unroll
      for (int w = 0; w < 8; ++w) sblk += wsum[w];
      atomicAdd(&gsum[s], (double)sblk);
    }
    ++ep;
    gsync(bar, ep);

    double sd = __hip_atomic_load(&gsum[s], __ATOMIC_ACQUIRE, __HIP_MEMORY_SCOPE_AGENT);
    float enorm = fmaxf(sqrtf((float)(sd / TOTD)), 1e-10f);
    if (enorm <= 1.0f) {
      t = t + h;
#pragma unroll
      for (int e = 0; e < 16; ++e) { y[e] = ysr[e]; k1r[e] = k7r[e]; }
      // FSAL: acc (rec of act7) is NOT reused; k1 regs carry it. acc dead.
    }
    float factor = fminf(fmaxf(0.9f * powf(enorm, -0.2f), 0.2f), 5.0f);
    dtv = dtv * factor;
  }

  // --- final output ---
#pragma unroll
  for (int m = 0; m < 2; ++m)
#pragma unroll
    for (int j = 0; j < 4; ++j)
#pragma unroll
      for (int n = 0; n < 2; ++n) {
        const int e = m * 8 + j * 2 + n;
        int row = rowBase + wv * 32 + m * 16 + lk * 4 + j;
        int col = colBase + n * 16 + lr;
        out[(size_t)row * 1024 + col] = y[e];
      }
}

extern "C" void kernel_launch(void* const* d_in, const int* in_sizes, int n_in,
                              void* d_out, int out_size, void* d_ws, size_t ws_size,
                              hipStream_t stream) {
  const float* inp = (const float*)d_in[0];
  const float* prev = (const float*)d_in[1];
  const float* tau = (const float*)d_in[2];
  const f4* W4 = (const f4*)d_in[3];
  const float* iw = (const float*)d_in[4];
  const float* bias = (const float*)d_in[5];
  float* out = (float*)d_out;

  char* ws = (char*)d_ws;
  const size_t MB = 1024 * 1024;
  int* bar = (int*)ws;                               // 128 ints
  double* gsum = (double*)(ws + 1024);               // 64 doubles
  _Float16* Wh = (_Float16*)(ws + 64 * 1024);        // 2 MB
  _Float16* ab0 = (_Float16*)(ws + 64 * 1024 + 2 * MB);  // 4 MB
  _Float16* ab1 = (_Float16*)(ws + 64 * 1024 + 6 * MB);  // 4 MB

  k_zero<<<1, 128, 0, stream>>>(bar, gsum);
  k_ode<<<NBLK, NTHR, 0, stream>>>(inp, prev, tau, W4, iw, bias, out,
                                   bar, gsum, Wh, ab0, ab1);
}